// Round 11
// baseline (79750.909 us; speedup 1.0000x reference)
//
#include <hip/hip_runtime.h>

#define B_ 8
#define S_ 1024
#define C_ 512
#define H_ 8
#define D_ 64
#define P_ 16
#define SP_ 1040    // valid keys: S + P
#define SPAD_ 1088  // row stride for score matrix
#define KSZ 3

// Canary: fill d_out with 2.0f. Overwritten by conv2 on a healthy run;
// absmax ~4.5 signature if the pipeline dies mid-way.
__global__ void TCNAttentionBlock_13477607375366_kernel(float* out, int n) {
  int gid = blockIdx.x * 256 + threadIdx.x;
  if (gid < n) out[gid] = 2.0f;
}

// QKV projection, one thread per output element.
__global__ void k_qkv(const float* x, const float* Wq, const float* Wk,
                      const float* Wv, float* qb, float* kb, float* vb) {
  int gid = blockIdx.x * 256 + threadIdx.x;  // 3*B*H*S*D
  int d = gid & 63;
  int t = gid >> 6;
  int s = t & 1023; t >>= 10;
  int h = t & 7; t >>= 3;
  int n = t & 7;
  int mat = t >> 3;
  const float* W = (mat == 0) ? Wq : ((mat == 1) ? Wk : Wv);
  float acc = 0.f;
  for (int j = 0; j < 64; ++j)
    acc += x[((size_t)(n * S_ + s)) * C_ + h * 64 + j] * W[d * 64 + j];
  if (mat == 0)
    qb[((size_t)(n * H_ + h) * S_ + s) * D_ + d] = acc;
  else if (mat == 1)
    kb[((size_t)(n * H_ + h) * SPAD_ + s) * D_ + d] = acc;
  else
    vb[((size_t)(n * H_ + h) * SPAD_ + s) * D_ + d] = acc;
}

// Prefix rows [S, SP): broadcast p_keys/p_values to every (n,h).
__global__ void k_prefix(const float* pk, const float* pv, float* kb,
                         float* vb) {
  int gid = blockIdx.x * 256 + threadIdx.x;  // 64*16*64
  int d = gid & 63;
  int t = gid >> 6;
  int p = t & 15;
  int nh = t >> 4;
  kb[((size_t)nh * SPAD_ + S_ + p) * D_ + d] = pk[p * 64 + d];
  vb[((size_t)nh * SPAD_ + S_ + p) * D_ + d] = pv[p * 64 + d];
}

// Raw scores for batch n: Sb[h][q][l] = q_h[q] . k_h[l], l < SP.
__global__ void k_energy(const float* qb, const float* kb, float* Sb, int n) {
  int gid = blockIdx.x * 256 + threadIdx.x;  // H*S*SPAD
  int l = gid % SPAD_;
  int t = gid / SPAD_;
  int q = t & 1023;
  int h = t >> 10;
  if (l >= SP_) return;
  const float* qp = qb + ((size_t)(n * H_ + h) * S_ + q) * D_;
  const float* kp = kb + ((size_t)(n * H_ + h) * SPAD_ + l) * D_;
  float acc = 0.f;
  for (int d = 0; d < 64; ++d) acc += qp[d] * kp[d];
  Sb[((size_t)h * S_ + q) * SPAD_ + l] = acc;
}

// Fused premix (W_pre + factorized ALiBi) + softmax + postmix (W_post),
// one thread per q, in place on Sb.
__global__ void k_smx(float* Sb, const float* Wpre, const float* Wpost) {
  int q = blockIdx.x * 256 + threadIdx.x;
  if (q >= S_) return;
  const float isc = 0.04419417382415922f;  // 1/sqrt(512)
  float wsum[8], m[8], sden[8];
  for (int i = 0; i < 8; ++i) {
    float s = 0.f;
    for (int j = 0; j < 8; ++j) s += Wpre[i * 8 + j] * exp2f(-(float)(j + 1));
    wsum[i] = s;
    m[i] = -1e30f;
    sden[i] = 0.f;
  }
  for (int l = 0; l < SP_; ++l) {
    float bt = (l < S_) ? -fabsf((float)(q - l)) : 0.0f;
    for (int i = 0; i < 8; ++i) {
      float e = bt * wsum[i];
      for (int j = 0; j < 8; ++j)
        e += Wpre[i * 8 + j] * Sb[((size_t)j * S_ + q) * SPAD_ + l];
      e *= isc;
      m[i] = fmaxf(m[i], e);
    }
  }
  for (int l = 0; l < SP_; ++l) {
    float bt = (l < S_) ? -fabsf((float)(q - l)) : 0.0f;
    for (int i = 0; i < 8; ++i) {
      float e = bt * wsum[i];
      for (int j = 0; j < 8; ++j)
        e += Wpre[i * 8 + j] * Sb[((size_t)j * S_ + q) * SPAD_ + l];
      e *= isc;
      sden[i] += __expf(e - m[i]);
    }
  }
  float inv[8];
  for (int i = 0; i < 8; ++i) inv[i] = 1.0f / sden[i];
  for (int l = 0; l < SP_; ++l) {
    float bt = (l < S_) ? -fabsf((float)(q - l)) : 0.0f;
    float a[8];
    for (int i = 0; i < 8; ++i) {
      float e = bt * wsum[i];
      for (int j = 0; j < 8; ++j)
        e += Wpre[i * 8 + j] * Sb[((size_t)j * S_ + q) * SPAD_ + l];
      e *= isc;
      a[i] = __expf(e - m[i]) * inv[i];
    }
    for (int o = 0; o < 8; ++o) {
      float v = 0.f;
      for (int i = 0; i < 8; ++i) v += Wpost[o * 8 + i] * a[i];
      Sb[((size_t)o * S_ + q) * SPAD_ + l] = v;
    }
  }
}

// AV for batch n: attb[n,q,h*64+d] = sum_l A2[h,q,l] * v[n,h,l,d]
__global__ void k_av(const float* Sb, const float* vb, float* attb, int n) {
  int gid = blockIdx.x * 256 + threadIdx.x;  // S*C
  int c = gid & 511;
  int q = gid >> 9;
  int h = c >> 6, d = c & 63;
  const float* ap = Sb + ((size_t)h * S_ + q) * SPAD_;
  const float* vp = vb + (size_t)(n * H_ + h) * SPAD_ * D_ + d;
  float acc = 0.f;
  for (int l = 0; l < SP_; ++l) acc += ap[l] * vp[(size_t)l * D_];
  attb[(size_t)(n * S_ + q) * C_ + c] = acc;
}

// FC + residual: hp = x + att @ Wfc^T + bfc
__global__ void k_fc(const float* attb, const float* Wfc, const float* bfc,
                     const float* x, float* hp) {
  int gid = blockIdx.x * 256 + threadIdx.x;  // B*S*C
  int c = gid & 511;
  int mrow = gid >> 9;
  const float* ap = attb + (size_t)mrow * C_;
  const float* wp = Wfc + (size_t)c * C_;
  float acc = 0.f;
  for (int k = 0; k < C_; ++k) acc += ap[k] * wp[k];
  hp[(size_t)mrow * C_ + c] = acc + bfc[c] + x[(size_t)mrow * C_ + c];
}

// LayerNorm over C, one thread per row.
__global__ void k_ln(const float* hp, const float* g, const float* b,
                     float* hb) {
  int r = blockIdx.x * 256 + threadIdx.x;  // B*S rows
  if (r >= B_ * S_) return;
  const float* p = hp + (size_t)r * C_;
  float s1 = 0.f, s2 = 0.f;
  for (int c = 0; c < C_; ++c) {
    s1 += p[c];
    s2 += p[c] * p[c];
  }
  float mu = s1 * (1.0f / C_);
  float var = s2 * (1.0f / C_) - mu * mu;
  float rs = rsqrtf(var + 1e-5f);
  float* o = hb + (size_t)r * C_;
  for (int c = 0; c < C_; ++c) o[c] = (p[c] - mu) * rs * g[c] + b[c];
}

// Causal conv (K=3, left pad 2), weights in original (CO,CI,K) layout.
// add_res: out = relu(relu(conv+bias) + res)
__global__ void k_conv(const float* in, const float* w, const float* bias,
                       const float* res, float* out, int add_res) {
  int gid = blockIdx.x * 256 + threadIdx.x;  // B*S*C
  int co = gid & 511;
  int t = gid >> 9;
  int s = t & 1023;
  int n = t >> 10;
  float acc = bias[co];
  for (int tap = 0; tap < KSZ; ++tap) {
    int s2 = s + tap - 2;
    if (s2 < 0) continue;
    const float* ip = in + (size_t)(n * S_ + s2) * C_;
    const float* wp = w + (size_t)co * C_ * KSZ + tap;
    for (int ci = 0; ci < C_; ++ci) acc += ip[ci] * wp[ci * KSZ];
  }
  float val = fmaxf(acc, 0.0f);
  if (add_res)
    val = fmaxf(val + res[(size_t)(n * S_ + s) * C_ + co], 0.0f);
  out[(size_t)(n * S_ + s) * C_ + co] = val;
}

extern "C" void kernel_launch(void* const* d_in, const int* in_sizes, int n_in,
                              void* d_out, int out_size, void* d_ws,
                              size_t ws_size, hipStream_t stream) {
  // Dict order (pad_mask at idx 1, 8192 elems) vs signature order (Wq, 4096).
  int o = (in_sizes[1] == D_ * D_) ? 1 : 2;
  const float* x = (const float*)d_in[0];
  const float* Wq = (const float*)d_in[o + 0];
  const float* Wk = (const float*)d_in[o + 1];
  const float* Wv = (const float*)d_in[o + 2];
  const float* Wfc = (const float*)d_in[o + 3];
  const float* bfc = (const float*)d_in[o + 4];
  const float* Wpre = (const float*)d_in[o + 5];
  const float* Wpost = (const float*)d_in[o + 6];
  const float* pk = (const float*)d_in[o + 7];
  const float* pv = (const float*)d_in[o + 8];
  const float* lng = (const float*)d_in[o + 9];
  const float* lnb = (const float*)d_in[o + 10];
  const float* c1w = (const float*)d_in[o + 11];
  const float* c1b = (const float*)d_in[o + 12];
  const float* c2w = (const float*)d_in[o + 13];
  const float* c2b = (const float*)d_in[o + 14];
  float* out = (float*)d_out;

  char* ws = (char*)d_ws;
  size_t off = 0;
  float* qb = (float*)(ws + off);  off += (size_t)B_ * H_ * S_ * D_ * 4;
  float* kb = (float*)(ws + off);  off += (size_t)B_ * H_ * SPAD_ * D_ * 4;
  float* vb = (float*)(ws + off);  off += (size_t)B_ * H_ * SPAD_ * D_ * 4;
  float* Sb = (float*)(ws + off);  off += (size_t)H_ * S_ * SPAD_ * 4;
  float* attb = (float*)(ws + off); off += (size_t)B_ * S_ * C_ * 4;
  // Aliases after last read of the source buffer:
  float* hpb = Sb;  // Sb dead after the attention loop
  float* hb = kb;   // kb dead after the attention loop
  float* o1b = qb;  // qb dead after the attention loop

  TCNAttentionBlock_13477607375366_kernel<<<(out_size + 255) / 256, 256, 0,
                                            stream>>>(out, out_size);
  k_qkv<<<49152, 256, 0, stream>>>(x, Wq, Wk, Wv, qb, kb, vb);
  k_prefix<<<256, 256, 0, stream>>>(pk, pv, kb, vb);
  for (int n = 0; n < B_; ++n) {
    k_energy<<<34816, 256, 0, stream>>>(qb, kb, Sb, n);
    k_smx<<<4, 256, 0, stream>>>(Sb, Wpre, Wpost);
    k_av<<<2048, 256, 0, stream>>>(Sb, vb, attb, n);
  }
  k_fc<<<16384, 256, 0, stream>>>(attb, Wfc, bfc, x, hpb);
  k_ln<<<32, 256, 0, stream>>>(hpb, lng, lnb, hb);
  k_conv<<<16384, 256, 0, stream>>>(hb, c1w, c1b, (const float*)0, o1b, 0);
  k_conv<<<16384, 256, 0, stream>>>(o1b, c2w, c2b, hb, out, 1);
}

// Round 12
// 2266.773 us; speedup vs baseline: 35.1826x; 35.1826x over previous
//
#include <hip/hip_runtime.h>

#define B_ 8
#define S_ 1024
#define C_ 512
#define H_ 8
#define D_ 64
#define P_ 16
#define SP_ 1040    // valid keys: S + P
#define SPAD_ 1088  // score-matrix row stride: 17*64
#define KSZ 3

// Canary: fill d_out with 2.0f; conv2 overwrites all of it on a healthy run.
__global__ void TCNAttentionBlock_13477607375366_kernel(float* out, int n) {
  int gid = blockIdx.x * 256 + threadIdx.x;
  if (gid < n) out[gid] = 2.0f;
}

// QKV: per (mat, head) NT-GEMM, M=B*S, N=64, K=64. 64x64 tile, 4x4/thread.
__global__ void k_qkv(const float* x, const float* Wq, const float* Wk,
                      const float* Wv, float* qb, float* kb, float* vb) {
  __shared__ float As[64][65];
  __shared__ float Bs[64][65];
  int tid = threadIdx.x;
  int m0 = blockIdx.x * 64;
  int mat = blockIdx.y >> 3, h = blockIdx.y & 7;
  const float* W = (mat == 0) ? Wq : ((mat == 1) ? Wk : Wv);
  for (int u = tid; u < 1024; u += 256) {
    int row = u >> 4, seg = u & 15;
    *(float4*)&As[row][seg * 4] =
        *(const float4*)&x[(size_t)(m0 + row) * C_ + h * 64 + seg * 4];
    *(float4*)&Bs[row][seg * 4] = *(const float4*)&W[row * 64 + seg * 4];
  }
  __syncthreads();
  int tx = tid & 15, ty = tid >> 4;
  float acc[4][4] = {};
  for (int kk = 0; kk < 64; ++kk) {
    float a[4], b[4];
    for (int i = 0; i < 4; ++i) a[i] = As[ty * 4 + i][kk];
    for (int j = 0; j < 4; ++j) b[j] = Bs[tx * 4 + j][kk];
    for (int i = 0; i < 4; ++i)
      for (int j = 0; j < 4; ++j) acc[i][j] += a[i] * b[j];
  }
  for (int i = 0; i < 4; ++i)
    for (int j = 0; j < 4; ++j) {
      int m = m0 + ty * 4 + i;
      int n = m >> 10, s = m & 1023;
      int d = tx * 4 + j;
      if (mat == 0)
        qb[((size_t)(n * H_ + h) * S_ + s) * D_ + d] = acc[i][j];
      else if (mat == 1)
        kb[((size_t)(n * H_ + h) * SPAD_ + s) * D_ + d] = acc[i][j];
      else
        vb[((size_t)(n * H_ + h) * SPAD_ + s) * D_ + d] = acc[i][j];
    }
}

// k/v rows [S, SPAD): prefix for p<P, zeros for the rest of the pad.
__global__ void k_prefix(const float* pk, const float* pv, float* kb,
                         float* vb) {
  int gid = blockIdx.x * 256 + threadIdx.x;  // 64 nh * 64 p * 64 d
  int d = gid & 63;
  int t = gid >> 6;
  int p = t & 63, nh = t >> 6;
  int l = S_ + p;
  kb[((size_t)nh * SPAD_ + l) * D_ + d] = (p < P_) ? pk[p * 64 + d] : 0.0f;
  vb[((size_t)nh * SPAD_ + l) * D_ + d] = (p < P_) ? pv[p * 64 + d] : 0.0f;
}

// Energy per (n,h): Sb[h][q][l] = q.k, 64x64 tile, K=64.
__global__ void k_energy(const float* qb, const float* kb, float* Sb, int n) {
  __shared__ float As[64][65];
  __shared__ float Bs[64][65];
  int tid = threadIdx.x;
  int l0 = blockIdx.x * 64, q0 = blockIdx.y * 64, h = blockIdx.z;
  const float* qsrc = qb + ((size_t)(n * H_ + h) * S_ + q0) * D_;
  const float* ksrc = kb + ((size_t)(n * H_ + h) * SPAD_ + l0) * D_;
  for (int u = tid; u < 1024; u += 256) {
    int row = u >> 4, seg = u & 15;
    *(float4*)&As[row][seg * 4] = *(const float4*)&qsrc[row * 64 + seg * 4];
    *(float4*)&Bs[row][seg * 4] = *(const float4*)&ksrc[row * 64 + seg * 4];
  }
  __syncthreads();
  int tx = tid & 15, ty = tid >> 4;
  float acc[4][4] = {};
  for (int kk = 0; kk < 64; ++kk) {
    float a[4], b[4];
    for (int i = 0; i < 4; ++i) a[i] = As[ty * 4 + i][kk];
    for (int j = 0; j < 4; ++j) b[j] = Bs[tx * 4 + j][kk];
    for (int i = 0; i < 4; ++i)
      for (int j = 0; j < 4; ++j) acc[i][j] += a[i] * b[j];
  }
  for (int i = 0; i < 4; ++i)
    for (int j = 0; j < 4; ++j)
      Sb[((size_t)h * S_ + q0 + ty * 4 + i) * SPAD_ + l0 + tx * 4 + j] =
          acc[i][j];
}

// Per q: premix (W_pre + factorized ALiBi), softmax over l<SP, postmix.
// Block = one q, 512 threads = 8 waves (one per head). LDS ~35.3 KB.
__global__ void k_smx(float* Sb, const float* Wpre, const float* Wpost) {
  __shared__ float S1[8][SPAD_];
  __shared__ float wpre_s[64], wpost_s[64];
  int tid = threadIdx.x;
  int q = blockIdx.x;
  if (tid < 64)
    wpre_s[tid] = Wpre[tid];
  else if (tid < 128)
    wpost_s[tid - 64] = Wpost[tid - 64];
  int w = tid >> 6, lane = tid & 63;
  float* row = Sb + ((size_t)w * S_ + q) * SPAD_;
  for (int j = 0; j < 17; ++j) S1[w][j * 64 + lane] = row[j * 64 + lane];
  __syncthreads();
  float wp8[8], wq8[8];
  for (int i = 0; i < 8; ++i) {
    wp8[i] = wpre_s[w * 8 + i];
    wq8[i] = wpost_s[w * 8 + i];
  }
  float wsum = 0.f;
  for (int i = 0; i < 8; ++i) wsum += wp8[i] * exp2f(-(float)(i + 1));
  const float isc = 0.04419417382415922f;  // 1/sqrt(512)
  float v[17];
  float mx = -1e30f;
  for (int j = 0; j < 17; ++j) {
    int l = j * 64 + lane;
    float e = 0.f;
    for (int i = 0; i < 8; ++i) e += wp8[i] * S1[i][l];
    float bt = (l < S_) ? -fabsf((float)(q - l)) : 0.0f;
    e = (e + bt * wsum) * isc;
    if (l >= SP_) e = -1e30f;
    v[j] = e;
    mx = fmaxf(mx, e);
  }
  for (int m = 1; m < 64; m <<= 1) mx = fmaxf(mx, __shfl_xor(mx, m, 64));
  float s = 0.f;
  for (int j = 0; j < 17; ++j) {
    v[j] = __expf(v[j] - mx);
    s += v[j];
  }
  for (int m = 1; m < 64; m <<= 1) s += __shfl_xor(s, m, 64);
  float inv = 1.0f / s;
  __syncthreads();  // all premix reads done before overwrite
  for (int j = 0; j < 17; ++j) S1[w][j * 64 + lane] = v[j] * inv;
  __syncthreads();
  for (int j = 0; j < 17; ++j) {
    int l = j * 64 + lane;
    float a = 0.f;
    for (int i = 0; i < 8; ++i) a += wq8[i] * S1[i][l];
    row[l] = a;  // pad columns become 0 (attn=0 there)
  }
}

// AV per (n,h): attb[n,q,h*64+d] = sum_l A2[h,q,l] * v[n,h,l,d].
// B-tile transposes v inside the LDS load (no vtb buffer).
__global__ void k_av(const float* Sb, const float* vb, float* attb, int n) {
  __shared__ float As[64][33];
  __shared__ float Bs[64][33];
  int tid = threadIdx.x;
  int q0 = blockIdx.x * 64;
  int h = blockIdx.y;
  const float* Ab = Sb + ((size_t)h * S_ + q0) * SPAD_;
  const float* Vb = vb + (size_t)(n * H_ + h) * SPAD_ * D_;
  int tx = tid & 15, ty = tid >> 4;
  float acc[4][4] = {};
  for (int ks = 0; ks < 17; ++ks) {
    int k0 = ks * 64;  // two 32-wide sub-tiles per 64 to reuse As/Bs shape
    for (int half = 0; half < 2; ++half) {
      int kb0 = k0 + half * 32;
      __syncthreads();
      for (int u = tid; u < 512; u += 256) {
        int r = u >> 3, seg = u & 7;
        *(float4*)&As[r][seg * 4] =
            *(const float4*)&Ab[(size_t)r * SPAD_ + kb0 + seg * 4];
      }
      for (int u = tid; u < 2048; u += 256) {
        int kk = u >> 6, d = u & 63;
        Bs[d][kk] = Vb[(size_t)(kb0 + kk) * D_ + d];
      }
      __syncthreads();
      for (int kk = 0; kk < 32; ++kk) {
        float a[4], b[4];
        for (int i = 0; i < 4; ++i) a[i] = As[ty * 4 + i][kk];
        for (int j = 0; j < 4; ++j) b[j] = Bs[tx * 4 + j][kk];
        for (int i = 0; i < 4; ++i)
          for (int j = 0; j < 4; ++j) acc[i][j] += a[i] * b[j];
      }
    }
  }
  for (int i = 0; i < 4; ++i)
    for (int j = 0; j < 4; ++j)
      attb[((size_t)(n * S_ + q0 + ty * 4 + i)) * C_ + h * 64 + tx * 4 + j] =
          acc[i][j];
}

// FC + residual: hp = x + att @ Wfc^T + bfc. 64x64 tile, K-loop 16x32.
__global__ void k_fc(const float* attb, const float* Wfc, const float* bfc,
                     const float* x, float* hp) {
  __shared__ float As[64][33];
  __shared__ float Bs[64][33];
  int tid = threadIdx.x;
  int m0 = blockIdx.x * 64, n0 = blockIdx.y * 64;
  int tx = tid & 15, ty = tid >> 4;
  float acc[4][4] = {};
  for (int ks = 0; ks < 16; ++ks) {
    int k0 = ks * 32;
    __syncthreads();
    for (int u = tid; u < 512; u += 256) {
      int r = u >> 3, seg = u & 7;
      *(float4*)&As[r][seg * 4] =
          *(const float4*)&attb[(size_t)(m0 + r) * C_ + k0 + seg * 4];
      *(float4*)&Bs[r][seg * 4] =
          *(const float4*)&Wfc[(size_t)(n0 + r) * C_ + k0 + seg * 4];
    }
    __syncthreads();
    for (int kk = 0; kk < 32; ++kk) {
      float a[4], b[4];
      for (int i = 0; i < 4; ++i) a[i] = As[ty * 4 + i][kk];
      for (int j = 0; j < 4; ++j) b[j] = Bs[tx * 4 + j][kk];
      for (int i = 0; i < 4; ++i)
        for (int j = 0; j < 4; ++j) acc[i][j] += a[i] * b[j];
    }
  }
  for (int i = 0; i < 4; ++i)
    for (int j = 0; j < 4; ++j) {
      int m = m0 + ty * 4 + i;
      int c = n0 + tx * 4 + j;
      hp[(size_t)m * C_ + c] = acc[i][j] + bfc[c] + x[(size_t)m * C_ + c];
    }
}

// LayerNorm over C per row; block = 512 threads, one channel each.
__global__ void k_ln(const float* hp, const float* g, const float* b,
                     float* hb) {
  __shared__ float r1[8], r2[8];
  int row = blockIdx.x, tid = threadIdx.x;
  int w = tid >> 6, lane = tid & 63;
  float v = hp[(size_t)row * C_ + tid];
  float s1 = v, s2 = v * v;
  for (int m = 1; m < 64; m <<= 1) {
    s1 += __shfl_xor(s1, m, 64);
    s2 += __shfl_xor(s2, m, 64);
  }
  if (lane == 0) {
    r1[w] = s1;
    r2[w] = s2;
  }
  __syncthreads();
  float t1 = 0.f, t2 = 0.f;
  for (int i = 0; i < 8; ++i) {
    t1 += r1[i];
    t2 += r2[i];
  }
  float mu = t1 * (1.0f / C_);
  float var = t2 * (1.0f / C_) - mu * mu;
  float o = (v - mu) * rsqrtf(var + 1e-5f) * g[tid] + b[tid];
  hb[(size_t)row * C_ + tid] = o;
}

// conv weights (CO,CI,K) -> [tap][co][ci] for coalesced GEMM B-tiles.
__global__ void k_repack(const float* wsrc, float* wdst) {
  int e = blockIdx.x * 256 + threadIdx.x;  // 512*512*3
  int co = e / (C_ * KSZ);
  int rem = e - co * (C_ * KSZ);
  int ci = rem / KSZ;
  int tap = rem - ci * KSZ;
  wdst[(size_t)tap * C_ * C_ + co * C_ + ci] = wsrc[e];
}

// Causal conv (K=3, left pad 2) as 3 accumulated NT-GEMMs; tap t uses row
// s+t-2 (halo rows in As). add_res: out = relu(relu(acc+bias) + res).
__global__ void k_conv(const float* in, const float* wt, const float* bias,
                       const float* res, float* out, int add_res) {
  __shared__ float As[66][33];
  __shared__ float Bs[3][64][33];
  int tid = threadIdx.x;
  int m0 = blockIdx.x * 64, n0 = blockIdx.y * 64;
  int n = m0 >> 10, s0 = m0 & 1023;
  int tx = tid & 15, ty = tid >> 4;
  float acc[4][4] = {};
  for (int ks = 0; ks < 16; ++ks) {
    int k0 = ks * 32;
    __syncthreads();
    for (int u = tid; u < 528; u += 256) {
      int r = u >> 3, seg = u & 7;
      if (r < 66) {
        int s = s0 + r - 2;
        float4 pa = make_float4(0.f, 0.f, 0.f, 0.f);
        if (s >= 0)
          pa = *(const float4*)&in[((size_t)(n * S_ + s)) * C_ + k0 + seg * 4];
        *(float4*)&As[r][seg * 4] = pa;
      }
    }
    for (int u = tid; u < 1536; u += 256) {
      int tap = u >> 9, rr = (u >> 3) & 63, seg = u & 7;
      *(float4*)&Bs[tap][rr][seg * 4] = *(const float4*)&wt[
          (size_t)tap * C_ * C_ + (size_t)(n0 + rr) * C_ + k0 + seg * 4];
    }
    __syncthreads();
    for (int kk = 0; kk < 32; ++kk) {
      float a[6];
      for (int u = 0; u < 6; ++u) a[u] = As[ty * 4 + u][kk];
      for (int tap = 0; tap < 3; ++tap) {
        float b[4];
        for (int j = 0; j < 4; ++j) b[j] = Bs[tap][tx * 4 + j][kk];
        for (int i = 0; i < 4; ++i)
          for (int j = 0; j < 4; ++j) acc[i][j] += a[i + tap] * b[j];
      }
    }
  }
  for (int i = 0; i < 4; ++i)
    for (int j = 0; j < 4; ++j) {
      int s = s0 + ty * 4 + i;
      int c = n0 + tx * 4 + j;
      float val = fmaxf(acc[i][j] + bias[c], 0.0f);
      if (add_res)
        val = fmaxf(val + res[((size_t)(n * S_ + s)) * C_ + c], 0.0f);
      out[((size_t)(n * S_ + s)) * C_ + c] = val;
    }
}

extern "C" void kernel_launch(void* const* d_in, const int* in_sizes, int n_in,
                              void* d_out, int out_size, void* d_ws,
                              size_t ws_size, hipStream_t stream) {
  int o = (in_sizes[1] == D_ * D_) ? 1 : 2;  // dict vs signature order
  const float* x = (const float*)d_in[0];
  const float* Wq = (const float*)d_in[o + 0];
  const float* Wk = (const float*)d_in[o + 1];
  const float* Wv = (const float*)d_in[o + 2];
  const float* Wfc = (const float*)d_in[o + 3];
  const float* bfc = (const float*)d_in[o + 4];
  const float* Wpre = (const float*)d_in[o + 5];
  const float* Wpost = (const float*)d_in[o + 6];
  const float* pk = (const float*)d_in[o + 7];
  const float* pv = (const float*)d_in[o + 8];
  const float* lng = (const float*)d_in[o + 9];
  const float* lnb = (const float*)d_in[o + 10];
  const float* c1w = (const float*)d_in[o + 11];
  const float* c1b = (const float*)d_in[o + 12];
  const float* c2w = (const float*)d_in[o + 13];
  const float* c2b = (const float*)d_in[o + 14];
  float* out = (float*)d_out;

  char* ws = (char*)d_ws;
  size_t off = 0;
  float* qb = (float*)(ws + off);  off += (size_t)B_ * H_ * S_ * D_ * 4;
  float* kb = (float*)(ws + off);  off += (size_t)B_ * H_ * SPAD_ * D_ * 4;
  float* vb = (float*)(ws + off);  off += (size_t)B_ * H_ * SPAD_ * D_ * 4;
  float* Sb = (float*)(ws + off);  off += (size_t)H_ * S_ * SPAD_ * 4;
  float* attb = (float*)(ws + off); off += (size_t)B_ * S_ * C_ * 4;
  // Aliases, valid strictly after the source buffer's last read:
  float* hpb = Sb;                      // Sb dead after last k_av
  float* hb = kb;                       // kb dead after last k_energy
  float* o1b = qb;                      // qb dead after last k_energy
  float* w1t = vb;                      // vb dead after last k_av
  float* w2t = vb + (size_t)KSZ * C_ * C_;

  TCNAttentionBlock_13477607375366_kernel<<<(out_size + 255) / 256, 256, 0,
                                            stream>>>(out, out_size);
  k_qkv<<<dim3(128, 24), 256, 0, stream>>>(x, Wq, Wk, Wv, qb, kb, vb);
  k_prefix<<<1024, 256, 0, stream>>>(pk, pv, kb, vb);
  for (int n = 0; n < B_; ++n) {
    k_energy<<<dim3(17, 16, 8), 256, 0, stream>>>(qb, kb, Sb, n);
    k_smx<<<1024, 512, 0, stream>>>(Sb, Wpre, Wpost);
    k_av<<<dim3(16, 8), 256, 0, stream>>>(Sb, vb, attb, n);
  }
  k_fc<<<dim3(128, 8), 256, 0, stream>>>(attb, Wfc, bfc, x, hpb);
  k_ln<<<8192, 512, 0, stream>>>(hpb, lng, lnb, hb);
  k_repack<<<3072, 256, 0, stream>>>(c1w, w1t);
  k_repack<<<3072, 256, 0, stream>>>(c2w, w2t);
  k_conv<<<dim3(128, 8), 256, 0, stream>>>(hb, w1t, c1b, (const float*)0, o1b,
                                           0);
  k_conv<<<dim3(128, 8), 256, 0, stream>>>(o1b, w2t, c2b, hb, out, 1);
}

// Round 13
// 613.701 us; speedup vs baseline: 129.9508x; 3.6936x over previous
//
#include <hip/hip_runtime.h>

#define B_ 8
#define S_ 1024
#define C_ 512
#define H_ 8
#define D_ 64
#define P_ 16
#define SP_ 1040    // valid keys: S + P
#define SPAD_ 1088  // score-matrix row stride: 17*64
#define KSZ 3

typedef unsigned short u16;
typedef short bf16x8 __attribute__((ext_vector_type(8)));
typedef float f32x4 __attribute__((ext_vector_type(4)));

__device__ __forceinline__ float bf2f(u16 u) {
  return __uint_as_float(((unsigned int)u) << 16);
}
__device__ __forceinline__ u16 f2bf(float f) {
  unsigned int u = __float_as_uint(f);
  return (u16)((u + 0x7fffu + ((u >> 16) & 1u)) >> 16);
}
// Round 8 consecutive fp32 to bf16, packed as int4 (8 x u16).
__device__ __forceinline__ int4 pack8(const float* p) {
  unsigned int a = f2bf(p[0]) | ((unsigned int)f2bf(p[1]) << 16);
  unsigned int b = f2bf(p[2]) | ((unsigned int)f2bf(p[3]) << 16);
  unsigned int c = f2bf(p[4]) | ((unsigned int)f2bf(p[5]) << 16);
  unsigned int d = f2bf(p[6]) | ((unsigned int)f2bf(p[7]) << 16);
  int4 r;
  r.x = (int)a; r.y = (int)b; r.z = (int)c; r.w = (int)d;
  return r;
}

// Canary: fill d_out with 2.0f; conv2 overwrites all of it on a healthy run.
__global__ void TCNAttentionBlock_13477607375366_kernel(float* out, int n) {
  int gid = blockIdx.x * 256 + threadIdx.x;
  if (gid < n) out[gid] = 2.0f;
}

// Generic fp32 -> bf16 convert (for W_fc).
__global__ void k_cvt(const float* src, u16* dst, int n) {
  int gid = blockIdx.x * 256 + threadIdx.x;
  if (gid < n) dst[gid] = f2bf(src[gid]);
}

// conv weights (CO,CI,K) fp32 -> [tap][co][ci] bf16.
__global__ void k_repack(const float* wsrc, u16* wdst) {
  int e = blockIdx.x * 256 + threadIdx.x;  // 512*512*3
  int co = e / (C_ * KSZ);
  int rem = e - co * (C_ * KSZ);
  int ci = rem / KSZ;
  int tap = rem - ci * KSZ;
  wdst[(size_t)tap * C_ * C_ + co * C_ + ci] = f2bf(wsrc[e]);
}

// QKV: per (mat, head) NT-GEMM via MFMA, M=B*S, N=64, K=64. bf16 out.
__global__ __launch_bounds__(256) void k_qkv(
    const float* x, const float* Wq, const float* Wk, const float* Wv,
    u16* qb, u16* kb, u16* vb) {
  __shared__ u16 As[64][72];
  __shared__ u16 Bs[64][72];
  int tid = threadIdx.x;
  int m0 = blockIdx.x * 64;
  int mat = blockIdx.y >> 3, h = blockIdx.y & 7;
  const float* W = (mat == 0) ? Wq : ((mat == 1) ? Wk : Wv);
  for (int u = tid; u < 512; u += 256) {
    int row = u >> 3, seg = u & 7;
    *(int4*)&As[row][seg * 8] =
        pack8(&x[(size_t)(m0 + row) * C_ + h * 64 + seg * 8]);
    *(int4*)&Bs[row][seg * 8] = pack8(&W[row * 64 + seg * 8]);
  }
  __syncthreads();
  int w = tid >> 6, lane = tid & 63, qd = lane >> 4, l15 = lane & 15;
  f32x4 acc[4] = {};
  for (int ks = 0; ks < 2; ++ks) {
    bf16x8 a = *(const bf16x8*)&As[w * 16 + l15][ks * 32 + qd * 8];
    for (int t = 0; t < 4; ++t) {
      bf16x8 b = *(const bf16x8*)&Bs[t * 16 + l15][ks * 32 + qd * 8];
      acc[t] = __builtin_amdgcn_mfma_f32_16x16x32_bf16(a, b, acc[t], 0, 0, 0);
    }
  }
  for (int t = 0; t < 4; ++t)
    for (int r = 0; r < 4; ++r) {
      int m = m0 + w * 16 + qd * 4 + r;
      int n = m >> 10, s = m & 1023;
      int d = t * 16 + l15;
      u16 val = f2bf(acc[t][r]);
      if (mat == 0)
        qb[((size_t)(n * H_ + h) * S_ + s) * D_ + d] = val;
      else if (mat == 1)
        kb[((size_t)(n * H_ + h) * SPAD_ + s) * D_ + d] = val;
      else
        vb[((size_t)(n * H_ + h) * SPAD_ + s) * D_ + d] = val;
    }
}

// k/v rows [S, SPAD): prefix bf16 for p<P, zeros for the rest.
__global__ void k_prefix(const float* pk, const float* pv, u16* kb, u16* vb) {
  int gid = blockIdx.x * 256 + threadIdx.x;  // 64 nh * 64 p * 64 d
  int d = gid & 63;
  int t = gid >> 6;
  int p = t & 63, nh = t >> 6;
  int l = S_ + p;
  kb[((size_t)nh * SPAD_ + l) * D_ + d] = (p < P_) ? f2bf(pk[p * 64 + d]) : 0;
  vb[((size_t)nh * SPAD_ + l) * D_ + d] = (p < P_) ? f2bf(pv[p * 64 + d]) : 0;
}

// v^T: vtb[nh][d][l] = vb[nh][l][d] (bf16).
__global__ void k_vtrans(const u16* vb, u16* vtb) {
  __shared__ u16 tile[64][65];
  int nh = blockIdx.y, l0 = blockIdx.x * 64, tid = threadIdx.x;
  for (int u = tid; u < 4096; u += 256) {
    int r = u >> 6, c = u & 63;
    tile[r][c] = vb[((size_t)nh * SPAD_ + l0 + r) * D_ + c];
  }
  __syncthreads();
  for (int u = tid; u < 4096; u += 256) {
    int d = u >> 6, c2 = u & 63;
    vtb[((size_t)nh * D_ + d) * SPAD_ + l0 + c2] = tile[c2][d];
  }
}

// Energy per (n,h): Sb[h][q][l] = q.k via MFMA, bf16 scores out.
__global__ __launch_bounds__(256) void k_energy(const u16* qb, const u16* kb,
                                                u16* Sb, int n) {
  __shared__ u16 As[64][72];
  __shared__ u16 Bs[64][72];
  int tid = threadIdx.x;
  int l0 = blockIdx.x * 64, q0 = blockIdx.y * 64, h = blockIdx.z;
  const u16* qsrc = qb + ((size_t)(n * H_ + h) * S_ + q0) * D_;
  const u16* ksrc = kb + ((size_t)(n * H_ + h) * SPAD_ + l0) * D_;
  for (int u = tid; u < 512; u += 256) {
    int row = u >> 3, seg = u & 7;
    *(int4*)&As[row][seg * 8] = *(const int4*)&qsrc[row * 64 + seg * 8];
    *(int4*)&Bs[row][seg * 8] = *(const int4*)&ksrc[row * 64 + seg * 8];
  }
  __syncthreads();
  int w = tid >> 6, lane = tid & 63, qd = lane >> 4, l15 = lane & 15;
  f32x4 acc[4] = {};
  for (int ks = 0; ks < 2; ++ks) {
    bf16x8 a = *(const bf16x8*)&As[w * 16 + l15][ks * 32 + qd * 8];
    for (int t = 0; t < 4; ++t) {
      bf16x8 b = *(const bf16x8*)&Bs[t * 16 + l15][ks * 32 + qd * 8];
      acc[t] = __builtin_amdgcn_mfma_f32_16x16x32_bf16(a, b, acc[t], 0, 0, 0);
    }
  }
  for (int t = 0; t < 4; ++t)
    for (int r = 0; r < 4; ++r) {
      int q = q0 + w * 16 + qd * 4 + r;
      int l = l0 + t * 16 + l15;
      Sb[((size_t)h * S_ + q) * SPAD_ + l] = f2bf(acc[t][r]);
    }
}

// Per q: premix (W_pre + factorized ALiBi), softmax over l<SP, postmix.
// Block = one q, 512 thr = 8 waves. bf16 in/out, fp32 internal.
__global__ __launch_bounds__(512) void k_smx(u16* Sb, const float* Wpre,
                                             const float* Wpost) {
  __shared__ float S1[8][SPAD_];
  __shared__ float wpre_s[64], wpost_s[64];
  int tid = threadIdx.x;
  int q = blockIdx.x;
  if (tid < 64)
    wpre_s[tid] = Wpre[tid];
  else if (tid < 128)
    wpost_s[tid - 64] = Wpost[tid - 64];
  int w = tid >> 6, lane = tid & 63;
  u16* row = Sb + ((size_t)w * S_ + q) * SPAD_;
  for (int j = 0; j < 17; ++j) S1[w][j * 64 + lane] = bf2f(row[j * 64 + lane]);
  __syncthreads();
  float wp8[8], wq8[8];
  for (int i = 0; i < 8; ++i) {
    wp8[i] = wpre_s[w * 8 + i];
    wq8[i] = wpost_s[w * 8 + i];
  }
  float wsum = 0.f;
  for (int i = 0; i < 8; ++i) wsum += wp8[i] * exp2f(-(float)(i + 1));
  const float isc = 0.04419417382415922f;  // 1/sqrt(512)
  float v[17];
  float mx = -1e30f;
  for (int j = 0; j < 17; ++j) {
    int l = j * 64 + lane;
    float e = 0.f;
    for (int i = 0; i < 8; ++i) e += wp8[i] * S1[i][l];
    float bt = (l < S_) ? -fabsf((float)(q - l)) : 0.0f;
    e = (e + bt * wsum) * isc;
    if (l >= SP_) e = -1e30f;
    v[j] = e;
    mx = fmaxf(mx, e);
  }
  for (int m = 1; m < 64; m <<= 1) mx = fmaxf(mx, __shfl_xor(mx, m, 64));
  float s = 0.f;
  for (int j = 0; j < 17; ++j) {
    v[j] = __expf(v[j] - mx);
    s += v[j];
  }
  for (int m = 1; m < 64; m <<= 1) s += __shfl_xor(s, m, 64);
  float inv = 1.0f / s;
  __syncthreads();  // premix reads complete before overwrite
  for (int j = 0; j < 17; ++j) S1[w][j * 64 + lane] = v[j] * inv;
  __syncthreads();
  for (int j = 0; j < 17; ++j) {
    int l = j * 64 + lane;
    float a = 0.f;
    for (int i = 0; i < 8; ++i) a += wq8[i] * S1[i][l];
    row[l] = f2bf(a);
  }
}

// AV per (n,h): attb[n,q,h*64+d] = sum_l attn[h,q,l]*v[l,d] via MFMA.
__global__ __launch_bounds__(256) void k_av(const u16* Sb, const u16* vtb,
                                            u16* attb, int n) {
  __shared__ u16 As[64][40];
  __shared__ u16 Bs[64][40];
  int tid = threadIdx.x;
  int q0 = blockIdx.x * 64, h = blockIdx.y;
  const u16* Ab = Sb + ((size_t)h * S_ + q0) * SPAD_;
  const u16* Bb = vtb + (size_t)(n * H_ + h) * D_ * SPAD_;
  int w = tid >> 6, lane = tid & 63, qd = lane >> 4, l15 = lane & 15;
  int row = tid >> 2, seg = tid & 3;
  f32x4 acc[4] = {};
  for (int ks = 0; ks < 34; ++ks) {
    int k0 = ks * 32;
    __syncthreads();
    *(int4*)&As[row][seg * 8] =
        *(const int4*)&Ab[(size_t)row * SPAD_ + k0 + seg * 8];
    *(int4*)&Bs[row][seg * 8] =
        *(const int4*)&Bb[(size_t)row * SPAD_ + k0 + seg * 8];
    __syncthreads();
    bf16x8 a = *(const bf16x8*)&As[w * 16 + l15][qd * 8];
    for (int t = 0; t < 4; ++t) {
      bf16x8 b = *(const bf16x8*)&Bs[t * 16 + l15][qd * 8];
      acc[t] = __builtin_amdgcn_mfma_f32_16x16x32_bf16(a, b, acc[t], 0, 0, 0);
    }
  }
  for (int t = 0; t < 4; ++t)
    for (int r = 0; r < 4; ++r) {
      int q = q0 + w * 16 + qd * 4 + r;
      int c = h * 64 + t * 16 + l15;
      attb[((size_t)(n * S_ + q)) * C_ + c] = f2bf(acc[t][r]);
    }
}

// FC + residual: hp = x + att @ Wfc^T + bfc (fp32 out).
__global__ __launch_bounds__(256) void k_fc(const u16* attb, const u16* Wfcb,
                                            const float* bfc, const float* x,
                                            float* hp) {
  __shared__ u16 As[64][40];
  __shared__ u16 Bs[64][40];
  int tid = threadIdx.x;
  int m0 = blockIdx.x * 64, n0 = blockIdx.y * 64;
  int w = tid >> 6, lane = tid & 63, qd = lane >> 4, l15 = lane & 15;
  int row = tid >> 2, seg = tid & 3;
  f32x4 acc[4] = {};
  for (int ks = 0; ks < 16; ++ks) {
    int k0 = ks * 32;
    __syncthreads();
    *(int4*)&As[row][seg * 8] =
        *(const int4*)&attb[(size_t)(m0 + row) * C_ + k0 + seg * 8];
    *(int4*)&Bs[row][seg * 8] =
        *(const int4*)&Wfcb[(size_t)(n0 + row) * C_ + k0 + seg * 8];
    __syncthreads();
    bf16x8 a = *(const bf16x8*)&As[w * 16 + l15][qd * 8];
    for (int t = 0; t < 4; ++t) {
      bf16x8 b = *(const bf16x8*)&Bs[t * 16 + l15][qd * 8];
      acc[t] = __builtin_amdgcn_mfma_f32_16x16x32_bf16(a, b, acc[t], 0, 0, 0);
    }
  }
  for (int t = 0; t < 4; ++t)
    for (int r = 0; r < 4; ++r) {
      int m = m0 + w * 16 + qd * 4 + r;
      int c = n0 + t * 16 + l15;
      hp[(size_t)m * C_ + c] = acc[t][r] + bfc[c] + x[(size_t)m * C_ + c];
    }
}

// LayerNorm over C per row; fp32 in, bf16 out.
__global__ __launch_bounds__(512) void k_ln(const float* hp, const float* g,
                                            const float* b, u16* hb) {
  __shared__ float r1[8], r2[8];
  int row = blockIdx.x, tid = threadIdx.x;
  int w = tid >> 6, lane = tid & 63;
  float v = hp[(size_t)row * C_ + tid];
  float s1 = v, s2 = v * v;
  for (int m = 1; m < 64; m <<= 1) {
    s1 += __shfl_xor(s1, m, 64);
    s2 += __shfl_xor(s2, m, 64);
  }
  if (lane == 0) {
    r1[w] = s1;
    r2[w] = s2;
  }
  __syncthreads();
  float t1 = 0.f, t2 = 0.f;
  for (int i = 0; i < 8; ++i) {
    t1 += r1[i];
    t2 += r2[i];
  }
  float mu = t1 * (1.0f / C_);
  float var = t2 * (1.0f / C_) - mu * mu;
  float o = (v - mu) * rsqrtf(var + 1e-5f) * g[tid] + b[tid];
  hb[(size_t)row * C_ + tid] = f2bf(o);
}

// Causal conv (K=3, left pad 2) as 3 accumulated MFMA NT-GEMMs.
// mode 0: out = relu(acc+bias) -> outb bf16
// mode 1: out = relu(relu(acc+bias)+res) -> outf fp32
__global__ __launch_bounds__(256) void k_conv(const u16* in, const u16* wt,
                                              const float* bias,
                                              const u16* res, u16* outb,
                                              float* outf, int mode) {
  __shared__ u16 As[66][40];
  __shared__ u16 Bs[3][64][40];
  int tid = threadIdx.x;
  int m0 = blockIdx.x * 64, n0 = blockIdx.y * 64;
  int n = m0 >> 10, s0 = m0 & 1023;
  int w = tid >> 6, lane = tid & 63, qd = lane >> 4, l15 = lane & 15;
  f32x4 acc[4] = {};
  for (int ks = 0; ks < 16; ++ks) {
    int k0 = ks * 32;
    __syncthreads();
    for (int u = tid; u < 264; u += 256) {
      int row = u >> 2, seg = u & 3;
      int s = s0 + row - 2;
      int4 pa;
      pa.x = pa.y = pa.z = pa.w = 0;
      if (s >= 0)
        pa = *(const int4*)&in[((size_t)(n * S_ + s)) * C_ + k0 + seg * 8];
      *(int4*)&As[row][seg * 8] = pa;
    }
    for (int u = tid; u < 768; u += 256) {
      int tap = u >> 8, rr = (u >> 2) & 63, seg = u & 3;
      *(int4*)&Bs[tap][rr][seg * 8] = *(const int4*)&wt[
          (size_t)tap * C_ * C_ + (size_t)(n0 + rr) * C_ + k0 + seg * 8];
    }
    __syncthreads();
    for (int tap = 0; tap < 3; ++tap) {
      bf16x8 a = *(const bf16x8*)&As[w * 16 + l15 + tap][qd * 8];
      for (int t = 0; t < 4; ++t) {
        bf16x8 b = *(const bf16x8*)&Bs[tap][t * 16 + l15][qd * 8];
        acc[t] = __builtin_amdgcn_mfma_f32_16x16x32_bf16(a, b, acc[t], 0, 0, 0);
      }
    }
  }
  for (int t = 0; t < 4; ++t)
    for (int r = 0; r < 4; ++r) {
      int s = s0 + w * 16 + qd * 4 + r;
      int c = n0 + t * 16 + l15;
      float val = fmaxf(acc[t][r] + bias[c], 0.0f);
      size_t idx = ((size_t)(n * S_ + s)) * C_ + c;
      if (mode) {
        val = fmaxf(val + bf2f(res[idx]), 0.0f);
        outf[idx] = val;
      } else {
        outb[idx] = f2bf(val);
      }
    }
}

extern "C" void kernel_launch(void* const* d_in, const int* in_sizes, int n_in,
                              void* d_out, int out_size, void* d_ws,
                              size_t ws_size, hipStream_t stream) {
  int o = (in_sizes[1] == D_ * D_) ? 1 : 2;  // dict vs signature order
  const float* x = (const float*)d_in[0];
  const float* Wq = (const float*)d_in[o + 0];
  const float* Wk = (const float*)d_in[o + 1];
  const float* Wv = (const float*)d_in[o + 2];
  const float* Wfc = (const float*)d_in[o + 3];
  const float* bfc = (const float*)d_in[o + 4];
  const float* Wpre = (const float*)d_in[o + 5];
  const float* Wpost = (const float*)d_in[o + 6];
  const float* pk = (const float*)d_in[o + 7];
  const float* pv = (const float*)d_in[o + 8];
  const float* lng = (const float*)d_in[o + 9];
  const float* lnb = (const float*)d_in[o + 10];
  const float* c1w = (const float*)d_in[o + 11];
  const float* c1b = (const float*)d_in[o + 12];
  const float* c2w = (const float*)d_in[o + 13];
  const float* c2b = (const float*)d_in[o + 14];
  float* out = (float*)d_out;

  // Workspace ~98.6 MB, no aliasing (r11 proved >= 104.9 MB available).
  char* ws = (char*)d_ws;
  size_t off = 0;
  u16* qb = (u16*)(ws + off);   off += (size_t)B_ * H_ * S_ * D_ * 2;
  u16* kb = (u16*)(ws + off);   off += (size_t)B_ * H_ * SPAD_ * D_ * 2;
  u16* vb = (u16*)(ws + off);   off += (size_t)B_ * H_ * SPAD_ * D_ * 2;
  u16* vtb = (u16*)(ws + off);  off += (size_t)B_ * H_ * D_ * SPAD_ * 2;
  u16* Sb = (u16*)(ws + off);   off += (size_t)H_ * S_ * SPAD_ * 2;
  u16* attb = (u16*)(ws + off); off += (size_t)B_ * S_ * C_ * 2;
  float* hp = (float*)(ws + off); off += (size_t)B_ * S_ * C_ * 4;
  u16* hb = (u16*)(ws + off);   off += (size_t)B_ * S_ * C_ * 2;
  u16* o1b = (u16*)(ws + off);  off += (size_t)B_ * S_ * C_ * 2;
  u16* wfcb = (u16*)(ws + off); off += (size_t)C_ * C_ * 2;
  u16* w1t = (u16*)(ws + off);  off += (size_t)KSZ * C_ * C_ * 2;
  u16* w2t = (u16*)(ws + off);  off += (size_t)KSZ * C_ * C_ * 2;

  TCNAttentionBlock_13477607375366_kernel<<<(out_size + 255) / 256, 256, 0,
                                            stream>>>(out, out_size);
  k_cvt<<<1024, 256, 0, stream>>>(Wfc, wfcb, C_ * C_);
  k_repack<<<3072, 256, 0, stream>>>(c1w, w1t);
  k_repack<<<3072, 256, 0, stream>>>(c2w, w2t);
  k_qkv<<<dim3(128, 24), 256, 0, stream>>>(x, Wq, Wk, Wv, qb, kb, vb);
  k_prefix<<<1024, 256, 0, stream>>>(pk, pv, kb, vb);
  k_vtrans<<<dim3(17, 64), 256, 0, stream>>>(vb, vtb);
  for (int n = 0; n < B_; ++n) {
    k_energy<<<dim3(17, 16, 8), 256, 0, stream>>>(qb, kb, Sb, n);
    k_smx<<<1024, 512, 0, stream>>>(Sb, Wpre, Wpost);
    k_av<<<dim3(16, 8), 256, 0, stream>>>(Sb, vtb, attb, n);
  }
  k_fc<<<dim3(128, 8), 256, 0, stream>>>(attb, wfcb, bfc, x, hp);
  k_ln<<<8192, 512, 0, stream>>>(hp, lng, lnb, hb);
  k_conv<<<dim3(128, 8), 256, 0, stream>>>(hb, w1t, c1b, (const u16*)0, o1b,
                                           (float*)0, 0);
  k_conv<<<dim3(128, 8), 256, 0, stream>>>(o1b, w2t, c2b, hb, (u16*)0, out, 1);
}

// Round 14
// 399.510 us; speedup vs baseline: 199.6218x; 1.5361x over previous
//
#include <hip/hip_runtime.h>

#define B_ 8
#define S_ 1024
#define C_ 512
#define H_ 8
#define D_ 64
#define P_ 16
#define SP_ 1040    // valid keys: S + P
#define SPAD_ 1088  // score-matrix row stride: 17*64
#define KSZ 3

typedef unsigned short u16;
typedef short bf16x8 __attribute__((ext_vector_type(8)));
typedef float f32x4 __attribute__((ext_vector_type(4)));

__device__ __forceinline__ float bf2f(u16 u) {
  return __uint_as_float(((unsigned int)u) << 16);
}
__device__ __forceinline__ u16 f2bf(float f) {
  unsigned int u = __float_as_uint(f);
  return (u16)((u + 0x7fffu + ((u >> 16) & 1u)) >> 16);
}
// Round 8 consecutive fp32 to bf16, packed as int4 (8 x u16).
__device__ __forceinline__ int4 pack8(const float* p) {
  unsigned int a = f2bf(p[0]) | ((unsigned int)f2bf(p[1]) << 16);
  unsigned int b = f2bf(p[2]) | ((unsigned int)f2bf(p[3]) << 16);
  unsigned int c = f2bf(p[4]) | ((unsigned int)f2bf(p[5]) << 16);
  unsigned int d = f2bf(p[6]) | ((unsigned int)f2bf(p[7]) << 16);
  int4 r;
  r.x = (int)a; r.y = (int)b; r.z = (int)c; r.w = (int)d;
  return r;
}

// Generic fp32 -> bf16 convert (for W_fc).
__global__ void k_cvt(const float* src, u16* dst, int n) {
  int gid = blockIdx.x * 256 + threadIdx.x;
  if (gid < n) dst[gid] = f2bf(src[gid]);
}

// conv weights (CO,CI,K) fp32 -> [tap][co][ci] bf16.
__global__ void k_repack(const float* wsrc, u16* wdst) {
  int e = blockIdx.x * 256 + threadIdx.x;  // 512*512*3
  int co = e / (C_ * KSZ);
  int rem = e - co * (C_ * KSZ);
  int ci = rem / KSZ;
  int tap = rem - ci * KSZ;
  wdst[(size_t)tap * C_ * C_ + co * C_ + ci] = f2bf(wsrc[e]);
}

// QKV: per (mat, head) NT-GEMM via MFMA, M=B*S, N=64, K=64. bf16 out.
__global__ __launch_bounds__(256) void k_qkv(
    const float* x, const float* Wq, const float* Wk, const float* Wv,
    u16* qb, u16* kb, u16* vb) {
  __shared__ u16 As[64][72];
  __shared__ u16 Bs[64][72];
  int tid = threadIdx.x;
  int m0 = blockIdx.x * 64;
  int mat = blockIdx.y >> 3, h = blockIdx.y & 7;
  const float* W = (mat == 0) ? Wq : ((mat == 1) ? Wk : Wv);
  for (int u = tid; u < 512; u += 256) {
    int row = u >> 3, seg = u & 7;
    *(int4*)&As[row][seg * 8] =
        pack8(&x[(size_t)(m0 + row) * C_ + h * 64 + seg * 8]);
    *(int4*)&Bs[row][seg * 8] = pack8(&W[row * 64 + seg * 8]);
  }
  __syncthreads();
  int w = tid >> 6, lane = tid & 63, qd = lane >> 4, l15 = lane & 15;
  f32x4 acc[4] = {};
  for (int ks = 0; ks < 2; ++ks) {
    bf16x8 a = *(const bf16x8*)&As[w * 16 + l15][ks * 32 + qd * 8];
    for (int t = 0; t < 4; ++t) {
      bf16x8 b = *(const bf16x8*)&Bs[t * 16 + l15][ks * 32 + qd * 8];
      acc[t] = __builtin_amdgcn_mfma_f32_16x16x32_bf16(a, b, acc[t], 0, 0, 0);
    }
  }
  for (int t = 0; t < 4; ++t)
    for (int r = 0; r < 4; ++r) {
      int m = m0 + w * 16 + qd * 4 + r;
      int n = m >> 10, s = m & 1023;
      int d = t * 16 + l15;
      u16 val = f2bf(acc[t][r]);
      if (mat == 0)
        qb[((size_t)(n * H_ + h) * S_ + s) * D_ + d] = val;
      else if (mat == 1)
        kb[((size_t)(n * H_ + h) * SPAD_ + s) * D_ + d] = val;
      else
        vb[((size_t)(n * H_ + h) * SPAD_ + s) * D_ + d] = val;
    }
}

// k/v rows [S, SPAD): prefix bf16 for p<P, zeros for the rest.
__global__ void k_prefix(const float* pk, const float* pv, u16* kb, u16* vb) {
  int gid = blockIdx.x * 256 + threadIdx.x;  // 64 nh * 64 p * 64 d
  int d = gid & 63;
  int t = gid >> 6;
  int p = t & 63, nh = t >> 6;
  int l = S_ + p;
  kb[((size_t)nh * SPAD_ + l) * D_ + d] = (p < P_) ? f2bf(pk[p * 64 + d]) : 0;
  vb[((size_t)nh * SPAD_ + l) * D_ + d] = (p < P_) ? f2bf(pv[p * 64 + d]) : 0;
}

// v^T: vtb[nh][d][l] = vb[nh][l][d] (bf16).
__global__ void k_vtrans(const u16* vb, u16* vtb) {
  __shared__ u16 tile[64][65];
  int nh = blockIdx.y, l0 = blockIdx.x * 64, tid = threadIdx.x;
  for (int u = tid; u < 4096; u += 256) {
    int r = u >> 6, c = u & 63;
    tile[r][c] = vb[((size_t)nh * SPAD_ + l0 + r) * D_ + c];
  }
  __syncthreads();
  for (int u = tid; u < 4096; u += 256) {
    int d = u >> 6, c2 = u & 63;
    vtb[((size_t)nh * D_ + d) * SPAD_ + l0 + c2] = tile[c2][d];
  }
}

// Energy, full batch: Sb[n,h][q][l] = q.k via MFMA, bf16 scores out.
__global__ __launch_bounds__(256) void k_energy(const u16* qb, const u16* kb,
                                                u16* Sb) {
  __shared__ u16 As[64][72];
  __shared__ u16 Bs[64][72];
  int tid = threadIdx.x;
  int l0 = blockIdx.x * 64, q0 = blockIdx.y * 64;
  int nh = blockIdx.z;  // n*H + h
  const u16* qsrc = qb + ((size_t)nh * S_ + q0) * D_;
  const u16* ksrc = kb + ((size_t)nh * SPAD_ + l0) * D_;
  for (int u = tid; u < 512; u += 256) {
    int row = u >> 3, seg = u & 7;
    *(int4*)&As[row][seg * 8] = *(const int4*)&qsrc[row * 64 + seg * 8];
    *(int4*)&Bs[row][seg * 8] = *(const int4*)&ksrc[row * 64 + seg * 8];
  }
  __syncthreads();
  int w = tid >> 6, lane = tid & 63, qd = lane >> 4, l15 = lane & 15;
  f32x4 acc[4] = {};
  for (int ks = 0; ks < 2; ++ks) {
    bf16x8 a = *(const bf16x8*)&As[w * 16 + l15][ks * 32 + qd * 8];
    for (int t = 0; t < 4; ++t) {
      bf16x8 b = *(const bf16x8*)&Bs[t * 16 + l15][ks * 32 + qd * 8];
      acc[t] = __builtin_amdgcn_mfma_f32_16x16x32_bf16(a, b, acc[t], 0, 0, 0);
    }
  }
  for (int t = 0; t < 4; ++t)
    for (int r = 0; r < 4; ++r) {
      int q = q0 + w * 16 + qd * 4 + r;
      int l = l0 + t * 16 + l15;
      Sb[((size_t)nh * S_ + q) * SPAD_ + l] = f2bf(acc[t][r]);
    }
}

// Per (n,q): premix (W_pre + factorized ALiBi), softmax over l<SP, postmix.
// Block = one (n,q), 512 thr = 8 waves. bf16 in/out, fp32 internal.
__global__ __launch_bounds__(512) void k_smx(u16* Sb, const float* Wpre,
                                             const float* Wpost) {
  __shared__ float S1[8][SPAD_];
  __shared__ float wpre_s[64], wpost_s[64];
  int tid = threadIdx.x;
  int n = blockIdx.x >> 10, q = blockIdx.x & 1023;
  if (tid < 64)
    wpre_s[tid] = Wpre[tid];
  else if (tid < 128)
    wpost_s[tid - 64] = Wpost[tid - 64];
  int w = tid >> 6, lane = tid & 63;
  u16* row = Sb + ((size_t)(n * H_ + w) * S_ + q) * SPAD_;
  for (int j = 0; j < 17; ++j) S1[w][j * 64 + lane] = bf2f(row[j * 64 + lane]);
  __syncthreads();
  float wp8[8], wq8[8];
  for (int i = 0; i < 8; ++i) {
    wp8[i] = wpre_s[w * 8 + i];
    wq8[i] = wpost_s[w * 8 + i];
  }
  float wsum = 0.f;
  for (int i = 0; i < 8; ++i) wsum += wp8[i] * exp2f(-(float)(i + 1));
  const float isc = 0.04419417382415922f;  // 1/sqrt(512)
  float v[17];
  float mx = -1e30f;
  for (int j = 0; j < 17; ++j) {
    int l = j * 64 + lane;
    float e = 0.f;
    for (int i = 0; i < 8; ++i) e += wp8[i] * S1[i][l];
    float bt = (l < S_) ? -fabsf((float)(q - l)) : 0.0f;
    e = (e + bt * wsum) * isc;
    if (l >= SP_) e = -1e30f;
    v[j] = e;
    mx = fmaxf(mx, e);
  }
  for (int m = 1; m < 64; m <<= 1) mx = fmaxf(mx, __shfl_xor(mx, m, 64));
  float s = 0.f;
  for (int j = 0; j < 17; ++j) {
    v[j] = __expf(v[j] - mx);
    s += v[j];
  }
  for (int m = 1; m < 64; m <<= 1) s += __shfl_xor(s, m, 64);
  float inv = 1.0f / s;
  __syncthreads();  // premix reads complete before overwrite
  for (int j = 0; j < 17; ++j) S1[w][j * 64 + lane] = v[j] * inv;
  __syncthreads();
  for (int j = 0; j < 17; ++j) {
    int l = j * 64 + lane;
    float a = 0.f;
    for (int i = 0; i < 8; ++i) a += wq8[i] * S1[i][l];
    row[l] = f2bf(a);
  }
}

// AV, full batch: attb[n,q,h*64+d] = sum_l attn[nh,q,l]*vT[nh,d,l] via MFMA.
__global__ __launch_bounds__(256) void k_av(const u16* Sb, const u16* vtb,
                                            u16* attb) {
  __shared__ u16 As[64][40];
  __shared__ u16 Bs[64][40];
  int tid = threadIdx.x;
  int q0 = blockIdx.x * 64;
  int nh = blockIdx.y;
  int n = nh >> 3, h = nh & 7;
  const u16* Ab = Sb + ((size_t)nh * S_ + q0) * SPAD_;
  const u16* Bb = vtb + (size_t)nh * D_ * SPAD_;
  int w = tid >> 6, lane = tid & 63, qd = lane >> 4, l15 = lane & 15;
  int row = tid >> 2, seg = tid & 3;
  f32x4 acc[4] = {};
  for (int ks = 0; ks < 34; ++ks) {
    int k0 = ks * 32;
    __syncthreads();
    *(int4*)&As[row][seg * 8] =
        *(const int4*)&Ab[(size_t)row * SPAD_ + k0 + seg * 8];
    *(int4*)&Bs[row][seg * 8] =
        *(const int4*)&Bb[(size_t)row * SPAD_ + k0 + seg * 8];
    __syncthreads();
    bf16x8 a = *(const bf16x8*)&As[w * 16 + l15][qd * 8];
    for (int t = 0; t < 4; ++t) {
      bf16x8 b = *(const bf16x8*)&Bs[t * 16 + l15][qd * 8];
      acc[t] = __builtin_amdgcn_mfma_f32_16x16x32_bf16(a, b, acc[t], 0, 0, 0);
    }
  }
  for (int t = 0; t < 4; ++t)
    for (int r = 0; r < 4; ++r) {
      int q = q0 + w * 16 + qd * 4 + r;
      int c = h * 64 + t * 16 + l15;
      attb[((size_t)(n * S_ + q)) * C_ + c] = f2bf(acc[t][r]);
    }
}

// FC + residual: hp = x + att @ Wfc^T + bfc (fp32 out).
__global__ __launch_bounds__(256) void k_fc(const u16* attb, const u16* Wfcb,
                                            const float* bfc, const float* x,
                                            float* hp) {
  __shared__ u16 As[64][40];
  __shared__ u16 Bs[64][40];
  int tid = threadIdx.x;
  int m0 = blockIdx.x * 64, n0 = blockIdx.y * 64;
  int w = tid >> 6, lane = tid & 63, qd = lane >> 4, l15 = lane & 15;
  int row = tid >> 2, seg = tid & 3;
  f32x4 acc[4] = {};
  for (int ks = 0; ks < 16; ++ks) {
    int k0 = ks * 32;
    __syncthreads();
    *(int4*)&As[row][seg * 8] =
        *(const int4*)&attb[(size_t)(m0 + row) * C_ + k0 + seg * 8];
    *(int4*)&Bs[row][seg * 8] =
        *(const int4*)&Wfcb[(size_t)(n0 + row) * C_ + k0 + seg * 8];
    __syncthreads();
    bf16x8 a = *(const bf16x8*)&As[w * 16 + l15][qd * 8];
    for (int t = 0; t < 4; ++t) {
      bf16x8 b = *(const bf16x8*)&Bs[t * 16 + l15][qd * 8];
      acc[t] = __builtin_amdgcn_mfma_f32_16x16x32_bf16(a, b, acc[t], 0, 0, 0);
    }
  }
  for (int t = 0; t < 4; ++t)
    for (int r = 0; r < 4; ++r) {
      int m = m0 + w * 16 + qd * 4 + r;
      int c = n0 + t * 16 + l15;
      hp[(size_t)m * C_ + c] = acc[t][r] + bfc[c] + x[(size_t)m * C_ + c];
    }
}

// LayerNorm over C per row; fp32 in, bf16 out.
__global__ __launch_bounds__(512) void k_ln(const float* hp, const float* g,
                                            const float* b, u16* hb) {
  __shared__ float r1[8], r2[8];
  int row = blockIdx.x, tid = threadIdx.x;
  int w = tid >> 6, lane = tid & 63;
  float v = hp[(size_t)row * C_ + tid];
  float s1 = v, s2 = v * v;
  for (int m = 1; m < 64; m <<= 1) {
    s1 += __shfl_xor(s1, m, 64);
    s2 += __shfl_xor(s2, m, 64);
  }
  if (lane == 0) {
    r1[w] = s1;
    r2[w] = s2;
  }
  __syncthreads();
  float t1 = 0.f, t2 = 0.f;
  for (int i = 0; i < 8; ++i) {
    t1 += r1[i];
    t2 += r2[i];
  }
  float mu = t1 * (1.0f / C_);
  float var = t2 * (1.0f / C_) - mu * mu;
  float o = (v - mu) * rsqrtf(var + 1e-5f) * g[tid] + b[tid];
  hb[(size_t)row * C_ + tid] = f2bf(o);
}

// Causal conv (K=3, left pad 2) as 3 accumulated MFMA NT-GEMMs.
// mode 0: out = relu(acc+bias) -> outb bf16
// mode 1: out = relu(relu(acc+bias)+res) -> outf fp32
__global__ __launch_bounds__(256) void k_conv(const u16* in, const u16* wt,
                                              const float* bias,
                                              const u16* res, u16* outb,
                                              float* outf, int mode) {
  __shared__ u16 As[66][40];
  __shared__ u16 Bs[3][64][40];
  int tid = threadIdx.x;
  int m0 = blockIdx.x * 64, n0 = blockIdx.y * 64;
  int n = m0 >> 10, s0 = m0 & 1023;
  int w = tid >> 6, lane = tid & 63, qd = lane >> 4, l15 = lane & 15;
  f32x4 acc[4] = {};
  for (int ks = 0; ks < 16; ++ks) {
    int k0 = ks * 32;
    __syncthreads();
    for (int u = tid; u < 264; u += 256) {
      int row = u >> 2, seg = u & 3;
      int s = s0 + row - 2;
      int4 pa;
      pa.x = pa.y = pa.z = pa.w = 0;
      if (s >= 0)
        pa = *(const int4*)&in[((size_t)(n * S_ + s)) * C_ + k0 + seg * 8];
      *(int4*)&As[row][seg * 8] = pa;
    }
    for (int u = tid; u < 768; u += 256) {
      int tap = u >> 8, rr = (u >> 2) & 63, seg = u & 3;
      *(int4*)&Bs[tap][rr][seg * 8] = *(const int4*)&wt[
          (size_t)tap * C_ * C_ + (size_t)(n0 + rr) * C_ + k0 + seg * 8];
    }
    __syncthreads();
    for (int tap = 0; tap < 3; ++tap) {
      bf16x8 a = *(const bf16x8*)&As[w * 16 + l15 + tap][qd * 8];
      for (int t = 0; t < 4; ++t) {
        bf16x8 b = *(const bf16x8*)&Bs[tap][t * 16 + l15][qd * 8];
        acc[t] = __builtin_amdgcn_mfma_f32_16x16x32_bf16(a, b, acc[t], 0, 0, 0);
      }
    }
  }
  for (int t = 0; t < 4; ++t)
    for (int r = 0; r < 4; ++r) {
      int s = s0 + w * 16 + qd * 4 + r;
      int c = n0 + t * 16 + l15;
      float val = fmaxf(acc[t][r] + bias[c], 0.0f);
      size_t idx = ((size_t)(n * S_ + s)) * C_ + c;
      if (mode) {
        val = fmaxf(val + bf2f(res[idx]), 0.0f);
        outf[idx] = val;
      } else {
        outb[idx] = f2bf(val);
      }
    }
}

extern "C" void kernel_launch(void* const* d_in, const int* in_sizes, int n_in,
                              void* d_out, int out_size, void* d_ws,
                              size_t ws_size, hipStream_t stream) {
  int o = (in_sizes[1] == D_ * D_) ? 1 : 2;  // dict vs signature order
  const float* x = (const float*)d_in[0];
  const float* Wq = (const float*)d_in[o + 0];
  const float* Wk = (const float*)d_in[o + 1];
  const float* Wv = (const float*)d_in[o + 2];
  const float* Wfc = (const float*)d_in[o + 3];
  const float* bfc = (const float*)d_in[o + 4];
  const float* Wpre = (const float*)d_in[o + 5];
  const float* Wpost = (const float*)d_in[o + 6];
  const float* pk = (const float*)d_in[o + 7];
  const float* pv = (const float*)d_in[o + 8];
  const float* lng = (const float*)d_in[o + 9];
  const float* lnb = (const float*)d_in[o + 10];
  const float* c1w = (const float*)d_in[o + 11];
  const float* c1b = (const float*)d_in[o + 12];
  const float* c2w = (const float*)d_in[o + 13];
  const float* c2b = (const float*)d_in[o + 14];
  float* out = (float*)d_out;

  // Workspace ~223 MB (ws_size = 256 MiB per the harness poison fill).
  char* ws = (char*)d_ws;
  size_t off = 0;
  u16* qb = (u16*)(ws + off);   off += (size_t)B_ * H_ * S_ * D_ * 2;
  u16* kb = (u16*)(ws + off);   off += (size_t)B_ * H_ * SPAD_ * D_ * 2;
  u16* vb = (u16*)(ws + off);   off += (size_t)B_ * H_ * SPAD_ * D_ * 2;
  u16* vtb = (u16*)(ws + off);  off += (size_t)B_ * H_ * D_ * SPAD_ * 2;
  u16* Sb = (u16*)(ws + off);   off += (size_t)B_ * H_ * S_ * SPAD_ * 2;  // 142.6MB
  u16* attb = (u16*)(ws + off); off += (size_t)B_ * S_ * C_ * 2;
  float* hp = (float*)(ws + off); off += (size_t)B_ * S_ * C_ * 4;
  u16* hb = (u16*)(ws + off);   off += (size_t)B_ * S_ * C_ * 2;
  u16* o1b = (u16*)(ws + off);  off += (size_t)B_ * S_ * C_ * 2;
  u16* wfcb = (u16*)(ws + off); off += (size_t)C_ * C_ * 2;
  u16* w1t = (u16*)(ws + off);  off += (size_t)KSZ * C_ * C_ * 2;
  u16* w2t = (u16*)(ws + off);  off += (size_t)KSZ * C_ * C_ * 2;

  k_cvt<<<1024, 256, 0, stream>>>(Wfc, wfcb, C_ * C_);
  k_repack<<<3072, 256, 0, stream>>>(c1w, w1t);
  k_repack<<<3072, 256, 0, stream>>>(c2w, w2t);
  k_qkv<<<dim3(128, 24), 256, 0, stream>>>(x, Wq, Wk, Wv, qb, kb, vb);
  k_prefix<<<1024, 256, 0, stream>>>(pk, pv, kb, vb);
  k_vtrans<<<dim3(17, 64), 256, 0, stream>>>(vb, vtb);
  k_energy<<<dim3(17, 16, 64), 256, 0, stream>>>(qb, kb, Sb);
  k_smx<<<8192, 512, 0, stream>>>(Sb, Wpre, Wpost);
  k_av<<<dim3(16, 64), 256, 0, stream>>>(Sb, vtb, attb);
  k_fc<<<dim3(128, 8), 256, 0, stream>>>(attb, wfcb, bfc, x, hp);
  k_ln<<<8192, 512, 0, stream>>>(hp, lng, lnb, hb);
  k_conv<<<dim3(128, 8), 256, 0, stream>>>(hb, w1t, c1b, (const u16*)0, o1b,
                                           (float*)0, 0);
  k_conv<<<dim3(128, 8), 256, 0, stream>>>(o1b, w2t, c2b, hb, (u16*)0, out, 1);
}